// Round 6
// baseline (227.259 us; speedup 1.0000x reference)
//
#include <hip/hip_runtime.h>

#define TT 32   // atoms per tile

typedef float vf4 __attribute__((ext_vector_type(4)));   // clang vector: OK for nontemporal builtin

// ---------------- zero out output ----------------
__global__ void zero_kernel(float* __restrict__ p, int n) {
    int i = blockIdx.x * blockDim.x + threadIdx.x;
    if (i < n) p[i] = 0.f;
}

__device__ __forceinline__ float sigm(float z) { return 1.f / (1.f + expf(-z)); }

__device__ __forceinline__ float f4c(const float4& v, int i) {
    switch (i) { case 0: return v.x; case 1: return v.y; case 2: return v.z; default: return v.w; }
}

// ---------------- fused MLP forward + backward (tile GEMM) ----------------
// One block = one 32-atom tile, 512 threads (8 waves) -> ~4.9 waves/SIMD for
// latency hiding (R4 had 2.4). Each thread: 1 atom x 8 outputs.
// Weights from GLOBAL (L1/L2-cached, off the LDS pipe). Activations in LDS,
// chunk-XOR swizzle key = row&7 (b128 reads across distinct rows conflict-free
// or 2-way at worst).
__global__ __launch_bounds__(512, 4) void mlp_fwd_bwd(
    const float* __restrict__ x,
    const float* __restrict__ W1, const float* __restrict__ b1,
    const float* __restrict__ W2, const float* __restrict__ b2,
    const float* __restrict__ W3, const float* __restrict__ b3,
    const int* __restrict__ indices,
    float* __restrict__ energy_out, float* __restrict__ dEdD, int natoms)
{
    __shared__ float h1s[TT * 128];  // 16 KB: h1, later dz1 in-place
    __shared__ float Ss[TT * 128];   // 16 KB: xs (stride 64), later g2 (stride 128)

    const int tid = threadIdx.x;
    const int jb  = tid & 15;    // 8-wide output block
    const int al  = tid >> 4;    // atom 0..31
    const int a0  = blockIdx.x * TT;
    const int j0  = jb * 8;
    const int keyA = al & 7;

    // per-thread bias / W3 fragments (8 j's)
    float bb1[8], bb2[8], ww3[8];
    {
        float4 t0 = *(const float4*)(b1 + j0), t1 = *(const float4*)(b1 + j0 + 4);
        float4 u0 = *(const float4*)(b2 + j0), u1 = *(const float4*)(b2 + j0 + 4);
        float4 v0 = *(const float4*)(W3 + j0), v1 = *(const float4*)(W3 + j0 + 4);
        #pragma unroll
        for (int q = 0; q < 4; ++q) {
            bb1[q] = f4c(t0, q); bb1[4+q] = f4c(t1, q);
            bb2[q] = f4c(u0, q); bb2[4+q] = f4c(u1, q);
            ww3[q] = f4c(v0, q); ww3[4+q] = f4c(v1, q);
        }
    }
    const float b3v = b3[0];

    // ---- stage x tile into Ss (row stride 64 = 16 chunks), swizzled ----
    {
        int r = tid >> 4, c4 = tid & 15;
        int a = a0 + r;
        float4 v = make_float4(0.f, 0.f, 0.f, 0.f);
        if (a < natoms) v = *(const float4*)(x + (size_t)a * 64 + c4 * 4);
        *(float4*)(Ss + r * 64 + ((c4 ^ (r & 7)) << 2)) = v;
    }
    __syncthreads();

    // ---- layer 1: z1[al][j] = b1 + sum_d xs[al][d] * W1[d][j] ----
    float acc[8];
    #pragma unroll
    for (int q = 0; q < 8; ++q) acc[q] = bb1[q];

    #pragma unroll 4
    for (int d0 = 0; d0 < 64; d0 += 4) {
        const float4 xa = *(const float4*)(Ss + al * 64 + (((d0 >> 2) ^ keyA) << 2));
        float4 wv[4][2];
        #pragma unroll
        for (int d = 0; d < 4; ++d) {
            const float* wp = W1 + (size_t)(d0 + d) * 128 + j0;
            wv[d][0] = *(const float4*)(wp);
            wv[d][1] = *(const float4*)(wp + 4);
        }
        #pragma unroll
        for (int d = 0; d < 4; ++d) {
            const float xv = f4c(xa, d);
            #pragma unroll
            for (int q = 0; q < 4; ++q) {
                acc[q]     += xv * f4c(wv[d][0], q);
                acc[4 + q] += xv * f4c(wv[d][1], q);
            }
        }
    }
    {
        float4 h0, h1v;
        h0.x = sigm(acc[0]); h0.y = sigm(acc[1]); h0.z = sigm(acc[2]); h0.w = sigm(acc[3]);
        h1v.x = sigm(acc[4]); h1v.y = sigm(acc[5]); h1v.z = sigm(acc[6]); h1v.w = sigm(acc[7]);
        *(float4*)(h1s + al * 128 + (((2 * jb) ^ keyA) << 2)) = h0;
        *(float4*)(h1s + al * 128 + (((2 * jb + 1) ^ keyA) << 2)) = h1v;
    }
    __syncthreads();

    // ---- layer 2: z2[al][j] = b2 + sum_k h1[al][k] * W2[k][j] ----
    #pragma unroll
    for (int q = 0; q < 8; ++q) acc[q] = bb2[q];

    #pragma unroll 4
    for (int k0 = 0; k0 < 128; k0 += 4) {
        const float4 ha = *(const float4*)(h1s + al * 128 + (((k0 >> 2) ^ keyA) << 2));
        float4 wv[4][2];
        #pragma unroll
        for (int d = 0; d < 4; ++d) {
            const float* wp = W2 + (size_t)(k0 + d) * 128 + j0;
            wv[d][0] = *(const float4*)(wp);
            wv[d][1] = *(const float4*)(wp + 4);
        }
        #pragma unroll
        for (int d = 0; d < 4; ++d) {
            const float hv = f4c(ha, d);
            #pragma unroll
            for (int q = 0; q < 4; ++q) {
                acc[q]     += hv * f4c(wv[d][0], q);
                acc[4 + q] += hv * f4c(wv[d][1], q);
            }
        }
    }
    // h2, energy partial, g2 -> Ss (stride 128, swizzled)
    {
        float h2v[8];
        float e = 0.f;
        #pragma unroll
        for (int q = 0; q < 8; ++q) { h2v[q] = sigm(acc[q]); e += h2v[q] * ww3[q]; }
        e += __shfl_xor(e, 1); e += __shfl_xor(e, 2);
        e += __shfl_xor(e, 4); e += __shfl_xor(e, 8);
        if (jb == 0) {
            int a = a0 + al;
            if (a < natoms) atomicAdd(&energy_out[indices[a]], e + b3v);
        }
        float4 g0, g1;
        g0.x = ww3[0] * h2v[0] * (1.f - h2v[0]);
        g0.y = ww3[1] * h2v[1] * (1.f - h2v[1]);
        g0.z = ww3[2] * h2v[2] * (1.f - h2v[2]);
        g0.w = ww3[3] * h2v[3] * (1.f - h2v[3]);
        g1.x = ww3[4] * h2v[4] * (1.f - h2v[4]);
        g1.y = ww3[5] * h2v[5] * (1.f - h2v[5]);
        g1.z = ww3[6] * h2v[6] * (1.f - h2v[6]);
        g1.w = ww3[7] * h2v[7] * (1.f - h2v[7]);
        *(float4*)(Ss + al * 128 + (((2 * jb) ^ keyA) << 2)) = g0;
        *(float4*)(Ss + al * 128 + (((2 * jb + 1) ^ keyA) << 2)) = g1;
    }
    __syncthreads();

    // ---- dh1[m][k] = sum_j g2[m][j] * W2[k][j]; dz1 = dh1*h1*(1-h1) in-place ----
    {
        const int m  = tid & 31;          // atom
        const int kb = tid >> 5;          // 8-wide k-block (coalesced W2 rows)
        const int k0b = kb * 8;
        const int keyM = m & 7;
        float acc2[8];
        #pragma unroll
        for (int q = 0; q < 8; ++q) acc2[q] = 0.f;

        #pragma unroll 4
        for (int jj = 0; jj < 128; jj += 4) {
            const float4 ga = *(const float4*)(Ss + m * 128 + (((jj >> 2) ^ keyM) << 2));
            float4 wv[8];
            #pragma unroll
            for (int q = 0; q < 8; ++q)
                wv[q] = *(const float4*)(W2 + (size_t)(k0b + q) * 128 + jj);
            #pragma unroll
            for (int q = 0; q < 8; ++q)
                #pragma unroll
                for (int d = 0; d < 4; ++d)
                    acc2[q] += f4c(ga, d) * f4c(wv[q], d);
        }
        float* pA = h1s + m * 128 + (((2 * kb) ^ keyM) << 2);
        float* pB = h1s + m * 128 + (((2 * kb + 1) ^ keyM) << 2);
        float4 hA = *(float4*)pA, hB = *(float4*)pB;
        float4 zA, zB;
        zA.x = acc2[0] * hA.x * (1.f - hA.x);
        zA.y = acc2[1] * hA.y * (1.f - hA.y);
        zA.z = acc2[2] * hA.z * (1.f - hA.z);
        zA.w = acc2[3] * hA.w * (1.f - hA.w);
        zB.x = acc2[4] * hB.x * (1.f - hB.x);
        zB.y = acc2[5] * hB.y * (1.f - hB.y);
        zB.z = acc2[6] * hB.z * (1.f - hB.z);
        zB.w = acc2[7] * hB.w * (1.f - hB.w);
        *(float4*)pA = zA; *(float4*)pB = zB;
    }
    __syncthreads();

    // ---- dEdD[m][d] = sum_k dz1[m][k] * W1[d][k] ----
    {
        const int m  = tid & 31;          // atom
        const int db = tid >> 5;          // 4-wide d-block (coalesced W1 rows)
        const int d0b = db * 4;
        const int keyM = m & 7;
        float acc3[4];
        #pragma unroll
        for (int q = 0; q < 4; ++q) acc3[q] = 0.f;

        #pragma unroll 4
        for (int k0 = 0; k0 < 128; k0 += 4) {
            const float4 za = *(const float4*)(h1s + m * 128 + (((k0 >> 2) ^ keyM) << 2));
            float4 wv[4];
            #pragma unroll
            for (int q = 0; q < 4; ++q)
                wv[q] = *(const float4*)(W1 + (size_t)(d0b + q) * 128 + k0);
            #pragma unroll
            for (int q = 0; q < 4; ++q)
                #pragma unroll
                for (int d = 0; d < 4; ++d)
                    acc3[q] += f4c(za, d) * f4c(wv[q], d);
        }
        int a = a0 + m;
        if (a < natoms) {
            float4 o; o.x = acc3[0]; o.y = acc3[1]; o.z = acc3[2]; o.w = acc3[3];
            *(float4*)(dEdD + (size_t)a * 64 + d0b) = o;
        }
    }
}

// ---------------- force accumulation ----------------
// 16 lanes per row, 4 rows per wave. xd streamed NON-TEMPORALLY (evict-first,
// keeps the 5 MB dEdD table L2-resident for its ~60x reuse); dEdD cached.
__global__ __launch_bounds__(256) void force_kernel(
    const float* __restrict__ xd,
    const int* __restrict__ unique_i, const int* __restrict__ unique_j,
    const float* __restrict__ dEdD,
    float* __restrict__ forces, int nderiv)
{
    const int tid = threadIdx.x;
    const int lane = tid & 63;
    const int wib = tid >> 6;
    const int gwave = blockIdx.x * 4 + wib;
    const int nwaves = gridDim.x * 4;
    const int sub = lane >> 4;
    const int t = lane & 15;
    const int ngroups = (nderiv + 3) >> 2;

    for (int g = gwave; g < ngroups; g += nwaves) {
        const int r = g * 4 + sub;
        float p = 0.f;
        int jdst = 0, ax = 0;
        const bool valid = (r < nderiv);
        if (valid) {
            const int ai = unique_i[r];
            const vf4 v = __builtin_nontemporal_load(((const vf4*)(xd + (size_t)r * 64)) + t);
            const float4 w = ((const float4*)(dEdD + (size_t)ai * 64))[t];
            p = v.x * w.x + v.y * w.y + v.z * w.z + v.w * w.w;
            jdst = unique_j[r];
            ax = r % 3;   // axis = tile([0,1,2]) by construction
        }
        p += __shfl_xor(p, 1);
        p += __shfl_xor(p, 2);
        p += __shfl_xor(p, 4);
        p += __shfl_xor(p, 8);
        if (t == 0 && valid) atomicAdd(&forces[jdst * 3 + ax], p);
    }
}

extern "C" void kernel_launch(void* const* d_in, const int* in_sizes, int n_in,
                              void* d_out, int out_size, void* d_ws, size_t ws_size,
                              hipStream_t stream) {
    const float* x        = (const float*)d_in[0];
    const float* xd       = (const float*)d_in[1];
    const int*   indices  = (const int*)d_in[2];
    const int*   unique_i = (const int*)d_in[6];
    const int*   unique_j = (const int*)d_in[7];
    const float* W1       = (const float*)d_in[8];
    const float* b1       = (const float*)d_in[9];
    const float* W2       = (const float*)d_in[10];
    const float* b2       = (const float*)d_in[11];
    const float* W3       = (const float*)d_in[12];
    const float* b3       = (const float*)d_in[13];

    const int natoms = in_sizes[2];
    const int nconf  = in_sizes[3];
    const int nderiv = in_sizes[6];

    float* out    = (float*)d_out;
    float* energy = out;
    float* forces = out + nconf;
    float* dEdD   = (float*)d_ws;

    const int ntiles = (natoms + TT - 1) / TT;

    zero_kernel<<<(out_size + 255) / 256, 256, 0, stream>>>(out, out_size);
    mlp_fwd_bwd<<<ntiles, 512, 0, stream>>>(x, W1, b1, W2, b2, W3, b3,
                                            indices, energy, dEdD, natoms);
    force_kernel<<<2048, 256, 0, stream>>>(xd, unique_i, unique_j, dEdD,
                                           forces, nderiv);
}